// Round 4
// baseline (205.846 us; speedup 1.0000x reference)
//
#include <hip/hip_runtime.h>
#include <math.h>

#define BB 1024
#define VV 50257
#define EE 128
#define TN 64
#define NVT ((VV + TN - 1) / TN)   /* 786 */

typedef __bf16 bf16x8 __attribute__((ext_vector_type(8)));
typedef float f32x4 __attribute__((ext_vector_type(4)));
typedef f32x4 __attribute__((aligned(4))) f32x4u;   // 4B-aligned vector store (VV odd)

static __device__ __forceinline__ unsigned short f2bf(float f) {
  unsigned int u = __float_as_uint(f);
  u += 0x7fffu + ((u >> 16) & 1u);
  return (unsigned short)(u >> 16);
}

// K1: find the one-hot index (and value) per row. xs is [BB][VV] f32, flat-divisible by 4.
__global__ void k_scan(const float* __restrict__ xs, int* __restrict__ idx,
                       float* __restrict__ vals) {
  const long total4 = (long)BB * VV / 4;
  const long stride = (long)gridDim.x * blockDim.x;
  for (long i = (long)blockIdx.x * blockDim.x + threadIdx.x; i < total4; i += stride) {
    float4 v = ((const float4*)xs)[i];
    if (v.x != 0.f || v.y != 0.f || v.z != 0.f || v.w != 0.f) {
      float vv[4] = {v.x, v.y, v.z, v.w};
#pragma unroll
      for (int c = 0; c < 4; c++) {
        if (vv[c] != 0.f) {
          long f = i * 4 + c;
          int b = (int)(f / VV);
          int p = (int)(f - (long)b * VV);
          idx[b] = p;
          vals[b] = vv[c];
        }
      }
    }
  }
}

// K2: EMBEDM f32 -> bf16 copy.
__global__ void k_cvt(const float* __restrict__ em, unsigned short* __restrict__ ebf) {
  const int total4 = VV * EE / 4;
  const int stride = gridDim.x * blockDim.x;
  for (int i = blockIdx.x * blockDim.x + threadIdx.x; i < total4; i += stride) {
    float4 v = ((const float4*)em)[i];
    ushort4 o;
    o.x = f2bf(v.x); o.y = f2bf(v.y); o.z = f2bf(v.z); o.w = f2bf(v.w);
    ((ushort4*)ebf)[i] = o;
  }
}

// K3: y[b] = (val * EMBEDM[idx[b]]) @ metric, stored bf16. One block (128 thr) per row.
__global__ void k_embed(const float* __restrict__ em, const float* __restrict__ metric,
                        const int* __restrict__ idx, const float* __restrict__ vals,
                        unsigned short* __restrict__ ybf) {
  __shared__ float x[EE];
  const int b = blockIdx.x;
  const int e = threadIdx.x;
  const int row = idx[b];
  const float val = vals[b];
  x[e] = em[(long)row * EE + e] * val;
  __syncthreads();
  float acc = 0.f;
#pragma unroll
  for (int k = 0; k < EE; k++) acc = fmaf(x[k], metric[k * EE + e], acc);
  ybf[b * EE + e] = f2bf(acc);
}

// ---- GEMM scores = Y @ E^T, swapped-operand MFMA (A = E tile -> M = vocab,
// B = Y rows -> N = batch). D layout: batch row = lane&15, vocab col =
// colbase + ns*16 + (lane>>4)*4 + reg. Each lane owns ONE batch row and 16
// vocab cols -> cheap row reduction (pass A) and float4 stores (pass B).
// VGPR budget: afr 64 + y 16 + acc 16 + temps -> target <=128 for 4 waves/SIMD.

template <bool PASS_B, bool TAIL>
static __device__ __forceinline__ void process_rb(const bf16x8 (&afr)[4][4],
                                                  const unsigned short* __restrict__ ybf,
                                                  int rowbase, int vt, int li, int g, int l,
                                                  int vbase_l,
                                                  float* __restrict__ pm, float* __restrict__ ps,
                                                  const float* __restrict__ lse,
                                                  float* __restrict__ out) {
  bf16x8 y[4];
  const bf16x8* yv = (const bf16x8*)(ybf + (size_t)(rowbase + li) * EE);
#pragma unroll
  for (int kk = 0; kk < 4; kk++) y[kk] = yv[kk * 4 + g];

  f32x4 acc[4];
#pragma unroll
  for (int ns = 0; ns < 4; ns++) acc[ns] = (f32x4){0.f, 0.f, 0.f, 0.f};
#pragma unroll
  for (int ns = 0; ns < 4; ns++)
#pragma unroll
    for (int kk = 0; kk < 4; kk++)
      acc[ns] = __builtin_amdgcn_mfma_f32_16x16x32_bf16(afr[ns][kk], y[kk], acc[ns], 0, 0, 0);

  const int row = rowbase + li;

  if (!PASS_B) {
    float m = -INFINITY;
#pragma unroll
    for (int ns = 0; ns < 4; ns++)
#pragma unroll
      for (int r = 0; r < 4; r++)
        if (!TAIL || vbase_l + ns * 16 + r < VV) m = fmaxf(m, acc[ns][r]);
    m = fmaxf(m, __shfl_xor(m, 16));
    m = fmaxf(m, __shfl_xor(m, 32));
    float s = 0.f;
#pragma unroll
    for (int ns = 0; ns < 4; ns++)
#pragma unroll
      for (int r = 0; r < 4; r++)
        if (!TAIL || vbase_l + ns * 16 + r < VV) s += __expf(acc[ns][r] - m);
    s += __shfl_xor(s, 16);
    s += __shfl_xor(s, 32);
    if (l < 16) {
      pm[(size_t)vt * BB + row] = m;   // column-major: wave's 16 rows = one 64B line
      ps[(size_t)vt * BB + row] = s;
    }
  } else {
    const float L = lse[row];
    float* orow = out + (size_t)row * VV;
#pragma unroll
    for (int ns = 0; ns < 4; ns++) {
      const int c = vbase_l + ns * 16;
      if (!TAIL || c + 3 < VV) {
        f32x4 v;
#pragma unroll
        for (int r = 0; r < 4; r++) v[r] = acc[ns][r] - L;
        *(f32x4u*)(orow + c) = v;
      } else {
#pragma unroll
        for (int r = 0; r < 4; r++)
          if (c + r < VV) orow[c + r] = acc[ns][r] - L;
      }
    }
  }
}

template <bool PASS_B, bool TAIL>
static __device__ __forceinline__ void gemm_tiles(const unsigned short* __restrict__ ybf,
                                                  const unsigned short* __restrict__ ebf,
                                                  int vt, int half,
                                                  float* __restrict__ pm, float* __restrict__ ps,
                                                  const float* __restrict__ lse,
                                                  float* __restrict__ out) {
  const int w = (threadIdx.x >> 6);
  const int l = threadIdx.x & 63;
  const int g = l >> 4;
  const int li = l & 15;
  const int colbase = vt * TN;
  const int vbase_l = colbase + g * 4;

  // A fragments (E rows = vocab cols of this tile), register-resident: [ns][kk]
  bf16x8 afr[4][4];
#pragma unroll
  for (int ns = 0; ns < 4; ns++) {
    const int c = colbase + ns * 16 + li;
    const int cc = (!TAIL || c < VV) ? c : VV - 1;   // clamp; masked in epilogue
    const bf16x8* ev = (const bf16x8*)(ebf + (size_t)cc * EE);
#pragma unroll
    for (int kk = 0; kk < 4; kk++) afr[ns][kk] = ev[kk * 4 + g];
  }

  const int rowstart = half * 512 + w * 16;
#pragma unroll
  for (int rb = 0; rb < 8; rb++)
    process_rb<PASS_B, TAIL>(afr, ybf, rowstart + rb * 64, vt, li, g, l, vbase_l,
                             pm, ps, lse, out);
}

__global__ __launch_bounds__(256, 4) void k_gemm_a(const unsigned short* __restrict__ ybf,
                                                   const unsigned short* __restrict__ ebf,
                                                   float* __restrict__ pm,
                                                   float* __restrict__ ps) {
  const int vt = blockIdx.x;
  const int half = blockIdx.y;
  if (vt < NVT - 1)
    gemm_tiles<false, false>(ybf, ebf, vt, half, pm, ps, nullptr, nullptr);
  else
    gemm_tiles<false, true>(ybf, ebf, vt, half, pm, ps, nullptr, nullptr);
}

__global__ __launch_bounds__(256, 4) void k_gemm_b(const unsigned short* __restrict__ ybf,
                                                   const unsigned short* __restrict__ ebf,
                                                   const float* __restrict__ lse,
                                                   float* __restrict__ out) {
  const int vt = blockIdx.x;
  const int half = blockIdx.y;
  if (vt < NVT - 1)
    gemm_tiles<true, false>(ybf, ebf, vt, half, nullptr, nullptr, lse, out);
  else
    gemm_tiles<true, true>(ybf, ebf, vt, half, nullptr, nullptr, lse, out);
}

// K5: combine per-tile partials into lse per row. One block (256 thr) per row.
// pm/ps are [vt][row] column-major.
__global__ void k_lse(const float* __restrict__ pm, const float* __restrict__ ps,
                      float* __restrict__ lse) {
  const int row = blockIdx.x;
  const int t = threadIdx.x;
  __shared__ float sm[4];
  __shared__ float ssum[4];

  float m = -INFINITY;
  for (int i = t; i < NVT; i += 256) m = fmaxf(m, pm[(size_t)i * BB + row]);
#pragma unroll
  for (int off = 32; off; off >>= 1) m = fmaxf(m, __shfl_xor(m, off));
  if ((t & 63) == 0) sm[t >> 6] = m;
  __syncthreads();
  m = fmaxf(fmaxf(sm[0], sm[1]), fmaxf(sm[2], sm[3]));

  float s = 0.f;
  for (int i = t; i < NVT; i += 256)
    s += ps[(size_t)i * BB + row] * __expf(pm[(size_t)i * BB + row] - m);
#pragma unroll
  for (int off = 32; off; off >>= 1) s += __shfl_xor(s, off);
  if ((t & 63) == 0) ssum[t >> 6] = s;
  __syncthreads();
  if (t == 0) lse[row] = m + logf(ssum[0] + ssum[1] + ssum[2] + ssum[3]);
}

extern "C" void kernel_launch(void* const* d_in, const int* in_sizes, int n_in,
                              void* d_out, int out_size, void* d_ws, size_t ws_size,
                              hipStream_t stream) {
  const float* xs = (const float*)d_in[0];
  const float* em = (const float*)d_in[1];
  const float* metric = (const float*)d_in[2];
  float* out = (float*)d_out;

  char* w = (char*)d_ws;
  int* idx = (int*)(w + 0);                                   // 4 KB
  float* vals = (float*)(w + 4096);                           // 4 KB
  float* lse = (float*)(w + 8192);                            // 4 KB
  unsigned short* ybf = (unsigned short*)(w + 12288);         // 256 KB
  unsigned short* ebf = (unsigned short*)(w + 12288 + 262144);                 // 12.87 MB
  float* pm = (float*)(w + 12288 + 262144 + 12865792);                         // 3.22 MB
  float* ps = (float*)(w + 12288 + 262144 + 12865792 + (size_t)NVT * BB * 4);  // 3.22 MB

  k_scan<<<2048, 256, 0, stream>>>(xs, idx, vals);
  k_cvt<<<2048, 256, 0, stream>>>(em, ebf);
  k_embed<<<BB, EE, 0, stream>>>(em, metric, idx, vals, ybf);
  k_gemm_a<<<dim3(NVT, 2), 256, 0, stream>>>(ybf, ebf, pm, ps);
  k_lse<<<BB, 256, 0, stream>>>(pm, ps, lse);
  k_gemm_b<<<dim3(NVT, 2), 256, 0, stream>>>(ybf, ebf, lse, out);
}

// Round 5
// 191.401 us; speedup vs baseline: 1.0755x; 1.0755x over previous
//
#include <hip/hip_runtime.h>
#include <math.h>

#define BB 1024
#define VV 50257
#define EE 128
#define TN 64
#define NVT ((VV + TN - 1) / TN)   /* 786 */

typedef __bf16 bf16x8 __attribute__((ext_vector_type(8)));
typedef float f32x4 __attribute__((ext_vector_type(4)));
typedef f32x4 __attribute__((aligned(4))) f32x4u;   // 4B-aligned vector store (VV odd)

typedef __attribute__((address_space(3))) void as3_void;
typedef const __attribute__((address_space(1))) void as1_void;

static __device__ __forceinline__ unsigned short f2bf(float f) {
  unsigned int u = __float_as_uint(f);
  u += 0x7fffu + ((u >> 16) & 1u);
  return (unsigned short)(u >> 16);
}

// K1: find the one-hot index (and value) per row.
__global__ void k_scan(const float* __restrict__ xs, int* __restrict__ idx,
                       float* __restrict__ vals) {
  const long total4 = (long)BB * VV / 4;
  const long stride = (long)gridDim.x * blockDim.x;
  for (long i = (long)blockIdx.x * blockDim.x + threadIdx.x; i < total4; i += stride) {
    float4 v = ((const float4*)xs)[i];
    if (v.x != 0.f || v.y != 0.f || v.z != 0.f || v.w != 0.f) {
      float vv[4] = {v.x, v.y, v.z, v.w};
#pragma unroll
      for (int c = 0; c < 4; c++) {
        if (vv[c] != 0.f) {
          long f = i * 4 + c;
          int b = (int)(f / VV);
          int p = (int)(f - (long)b * VV);
          idx[b] = p;
          vals[b] = vv[c];
        }
      }
    }
  }
}

// K2: EMBEDM f32 -> bf16 copy.
__global__ void k_cvt(const float* __restrict__ em, unsigned short* __restrict__ ebf) {
  const int total4 = VV * EE / 4;
  const int stride = gridDim.x * blockDim.x;
  for (int i = blockIdx.x * blockDim.x + threadIdx.x; i < total4; i += stride) {
    float4 v = ((const float4*)em)[i];
    ushort4 o;
    o.x = f2bf(v.x); o.y = f2bf(v.y); o.z = f2bf(v.z); o.w = f2bf(v.w);
    ((ushort4*)ebf)[i] = o;
  }
}

// K3: y[b] = (val * EMBEDM[idx[b]]) @ metric, stored bf16.
__global__ void k_embed(const float* __restrict__ em, const float* __restrict__ metric,
                        const int* __restrict__ idx, const float* __restrict__ vals,
                        unsigned short* __restrict__ ybf) {
  __shared__ float x[EE];
  const int b = blockIdx.x;
  const int e = threadIdx.x;
  const int row = idx[b];
  const float val = vals[b];
  x[e] = em[(long)row * EE + e] * val;
  __syncthreads();
  float acc = 0.f;
#pragma unroll
  for (int k = 0; k < EE; k++) acc = fmaf(x[k], metric[k * EE + e], acc);
  ybf[b * EE + e] = f2bf(acc);
}

// ---- GEMM scores = Y @ E^T, swapped operands (A = E rows -> M = vocab,
// B = Y rows -> N = batch). D: batch row = lane&15, vocab = ns*16+(lane>>4)*4+reg.
// Y-tiles (64 rows x 256 B = 16 KB) staged to LDS via global_load_lds, double
// buffered, counted vmcnt(4). LDS XOR-swizzle gr^=(row&7) applied by
// pre-swizzling the GLOBAL source (linear LDS dest) and XORing the ds_read addr.

static __device__ __forceinline__ void stageY(const unsigned short* __restrict__ ybf,
                                              char* ldsbuf, int tilebase, int w, int lane) {
#pragma unroll
  for (int i = 0; i < 4; i++) {
    const int row = w * 16 + i * 4 + (lane >> 4);   // row within 64-row tile
    const int gr = lane & 15;                       // 16B granule within 256B row
    const int sg = gr ^ (row & 7);                  // inverse-swizzled source granule
    const char* src = (const char*)(ybf + (size_t)(tilebase + row) * EE) + sg * 16;
    __builtin_amdgcn_global_load_lds((as1_void*)src, (as3_void*)(ldsbuf + w * 4096 + i * 1024),
                                     16, 0, 0);
  }
}

template <bool PASS_B, bool TAIL>
static __device__ __forceinline__ void process_rb(const bf16x8 (&afr)[4][4],
                                                  const char* __restrict__ ldsbuf,
                                                  int rowbase, int vt, int li, int g, int l,
                                                  int w, int vbase_l,
                                                  float* __restrict__ pm, float* __restrict__ ps,
                                                  const float* __restrict__ lse,
                                                  float* __restrict__ out) {
  bf16x8 y[4];
  const char* ybase = ldsbuf + (size_t)(w * 16 + li) * 256;
#pragma unroll
  for (int kk = 0; kk < 4; kk++)
    y[kk] = *(const bf16x8*)(ybase + (((kk * 4 + g) ^ (li & 7)) * 16));

  f32x4 acc[4];
#pragma unroll
  for (int ns = 0; ns < 4; ns++) acc[ns] = (f32x4){0.f, 0.f, 0.f, 0.f};
#pragma unroll
  for (int ns = 0; ns < 4; ns++)
#pragma unroll
    for (int kk = 0; kk < 4; kk++)
      acc[ns] = __builtin_amdgcn_mfma_f32_16x16x32_bf16(afr[ns][kk], y[kk], acc[ns], 0, 0, 0);

  const int row = rowbase + w * 16 + li;

  if (!PASS_B) {
    float m = -INFINITY;
#pragma unroll
    for (int ns = 0; ns < 4; ns++)
#pragma unroll
      for (int r = 0; r < 4; r++)
        if (!TAIL || vbase_l + ns * 16 + r < VV) m = fmaxf(m, acc[ns][r]);
    m = fmaxf(m, __shfl_xor(m, 16));
    m = fmaxf(m, __shfl_xor(m, 32));
    float s = 0.f;
#pragma unroll
    for (int ns = 0; ns < 4; ns++)
#pragma unroll
      for (int r = 0; r < 4; r++)
        if (!TAIL || vbase_l + ns * 16 + r < VV) s += __expf(acc[ns][r] - m);
    s += __shfl_xor(s, 16);
    s += __shfl_xor(s, 32);
    if (l < 16) {
      pm[(size_t)vt * BB + row] = m;
      ps[(size_t)vt * BB + row] = s;
    }
  } else {
    const float L = lse[row];
    float* orow = out + (size_t)row * VV;
#pragma unroll
    for (int ns = 0; ns < 4; ns++) {
      const int c = vbase_l + ns * 16;
      if (!TAIL || c + 3 < VV) {
        f32x4 v;
#pragma unroll
        for (int r = 0; r < 4; r++) v[r] = acc[ns][r] - L;
        *(f32x4u*)(orow + c) = v;
      } else {
#pragma unroll
        for (int r = 0; r < 4; r++)
          if (c + r < VV) orow[c + r] = acc[ns][r] - L;
      }
    }
  }
}

template <bool PASS_B, bool TAIL>
static __device__ __forceinline__ void gemm_tiles(const unsigned short* __restrict__ ybf,
                                                  const unsigned short* __restrict__ ebf,
                                                  char* __restrict__ lds0, char* __restrict__ lds1,
                                                  int vt, int half,
                                                  float* __restrict__ pm, float* __restrict__ ps,
                                                  const float* __restrict__ lse,
                                                  float* __restrict__ out) {
  const int w = threadIdx.x >> 6;
  const int l = threadIdx.x & 63;
  const int g = l >> 4;
  const int li = l & 15;
  const int colbase = vt * TN;
  const int vbase_l = colbase + g * 4;
  const int base = half * 512;

  // afr: E-tile in registers (one deep burst per block; latency amortized).
  bf16x8 afr[4][4];
#pragma unroll
  for (int ns = 0; ns < 4; ns++) {
    const int c = colbase + ns * 16 + li;
    const int cc = (!TAIL || c < VV) ? c : VV - 1;
    const bf16x8* ev = (const bf16x8*)(ebf + (size_t)cc * EE);
#pragma unroll
    for (int kk = 0; kk < 4; kk++) afr[ns][kk] = ev[kk * 4 + g];
  }

  // Prologue: stage tiles 0 and 1.
  stageY(ybf, lds0, base + 0 * 64, w, l);
  stageY(ybf, lds1, base + 1 * 64, w, l);
  __builtin_amdgcn_sched_barrier(0);

#pragma unroll
  for (int rb = 0; rb < 8; rb++) {
    // Wait for my stage(rb); leave stage(rb+1)'s 4 loads (and older stores) behind.
    if (rb < 7) asm volatile("s_waitcnt vmcnt(4)" ::: "memory");
    else        asm volatile("s_waitcnt vmcnt(0)" ::: "memory");
    __builtin_amdgcn_sched_barrier(0);
    __builtin_amdgcn_s_barrier();          // all waves' stage(rb) complete
    __builtin_amdgcn_sched_barrier(0);

    char* cur = (rb & 1) ? lds1 : lds0;
    process_rb<PASS_B, TAIL>(afr, cur, base + rb * 64, vt, li, g, l, w, vbase_l,
                             pm, ps, lse, out);

    __builtin_amdgcn_sched_barrier(0);
    __builtin_amdgcn_s_barrier();          // all waves done reading buf(rb&1)
    __builtin_amdgcn_sched_barrier(0);
    if (rb < 6) stageY(ybf, cur, base + (rb + 2) * 64, w, l);
    __builtin_amdgcn_sched_barrier(0);
  }
}

__global__ __launch_bounds__(256, 3) void k_gemm_a(const unsigned short* __restrict__ ybf,
                                                   const unsigned short* __restrict__ ebf,
                                                   float* __restrict__ pm,
                                                   float* __restrict__ ps) {
  __shared__ char ylds[2][16384];
  const int vt = blockIdx.x;
  const int half = blockIdx.y;
  if (vt < NVT - 1)
    gemm_tiles<false, false>(ybf, ebf, ylds[0], ylds[1], vt, half, pm, ps, nullptr, nullptr);
  else
    gemm_tiles<false, true>(ybf, ebf, ylds[0], ylds[1], vt, half, pm, ps, nullptr, nullptr);
}

__global__ __launch_bounds__(256, 3) void k_gemm_b(const unsigned short* __restrict__ ybf,
                                                   const unsigned short* __restrict__ ebf,
                                                   const float* __restrict__ lse,
                                                   float* __restrict__ out) {
  __shared__ char ylds[2][16384];
  const int vt = blockIdx.x;
  const int half = blockIdx.y;
  if (vt < NVT - 1)
    gemm_tiles<true, false>(ybf, ebf, ylds[0], ylds[1], vt, half, nullptr, nullptr, lse, out);
  else
    gemm_tiles<true, true>(ybf, ebf, ylds[0], ylds[1], vt, half, nullptr, nullptr, lse, out);
}

// K5: combine per-tile partials into lse per row. pm/ps are [vt][row].
__global__ void k_lse(const float* __restrict__ pm, const float* __restrict__ ps,
                      float* __restrict__ lse) {
  const int row = blockIdx.x;
  const int t = threadIdx.x;
  __shared__ float sm[4];
  __shared__ float ssum[4];

  float m = -INFINITY;
  for (int i = t; i < NVT; i += 256) m = fmaxf(m, pm[(size_t)i * BB + row]);
#pragma unroll
  for (int off = 32; off; off >>= 1) m = fmaxf(m, __shfl_xor(m, off));
  if ((t & 63) == 0) sm[t >> 6] = m;
  __syncthreads();
  m = fmaxf(fmaxf(sm[0], sm[1]), fmaxf(sm[2], sm[3]));

  float s = 0.f;
  for (int i = t; i < NVT; i += 256)
    s += ps[(size_t)i * BB + row] * __expf(pm[(size_t)i * BB + row] - m);
#pragma unroll
  for (int off = 32; off; off >>= 1) s += __shfl_xor(s, off);
  if ((t & 63) == 0) ssum[t >> 6] = s;
  __syncthreads();
  if (t == 0) lse[row] = m + logf(ssum[0] + ssum[1] + ssum[2] + ssum[3]);
}

extern "C" void kernel_launch(void* const* d_in, const int* in_sizes, int n_in,
                              void* d_out, int out_size, void* d_ws, size_t ws_size,
                              hipStream_t stream) {
  const float* xs = (const float*)d_in[0];
  const float* em = (const float*)d_in[1];
  const float* metric = (const float*)d_in[2];
  float* out = (float*)d_out;

  char* w = (char*)d_ws;
  int* idx = (int*)(w + 0);                                   // 4 KB
  float* vals = (float*)(w + 4096);                           // 4 KB
  float* lse = (float*)(w + 8192);                            // 4 KB
  unsigned short* ybf = (unsigned short*)(w + 12288);         // 256 KB
  unsigned short* ebf = (unsigned short*)(w + 12288 + 262144);                 // 12.87 MB
  float* pm = (float*)(w + 12288 + 262144 + 12865792);                         // 3.22 MB
  float* ps = (float*)(w + 12288 + 262144 + 12865792 + (size_t)NVT * BB * 4);  // 3.22 MB

  k_scan<<<2048, 256, 0, stream>>>(xs, idx, vals);
  k_cvt<<<2048, 256, 0, stream>>>(em, ebf);
  k_embed<<<BB, EE, 0, stream>>>(em, metric, idx, vals, ybf);
  k_gemm_a<<<dim3(NVT, 2), 256, 0, stream>>>(ybf, ebf, pm, ps);
  k_lse<<<BB, 256, 0, stream>>>(pm, ps, lse);
  k_gemm_b<<<dim3(NVT, 2), 256, 0, stream>>>(ybf, ebf, lse, out);
}

// Round 6
// 174.360 us; speedup vs baseline: 1.1806x; 1.0977x over previous
//
#include <hip/hip_runtime.h>
#include <math.h>

#define BB 1024
#define VV 50257
#define EE 128
#define RR 256                      /* rows per block */
#define CC 1024                     /* cols per block */
#define CH 64                       /* cols per staged E-chunk */
#define NCH (CC / CH)               /* 16 chunks */
#define NCB ((VV + CC - 1) / CC)    /* 50 col-blocks */

typedef __bf16 bf16x8 __attribute__((ext_vector_type(8)));
typedef float f32x4 __attribute__((ext_vector_type(4)));
typedef f32x4 __attribute__((aligned(4))) f32x4u;   // 4B-aligned vector store (VV odd)

typedef __attribute__((address_space(3))) void as3_void;
typedef const __attribute__((address_space(1))) void as1_void;

static __device__ __forceinline__ unsigned short f2bf(float f) {
  unsigned int u = __float_as_uint(f);
  u += 0x7fffu + ((u >> 16) & 1u);
  return (unsigned short)(u >> 16);
}

// K1: find the one-hot index (and value) per row.
__global__ void k_scan(const float* __restrict__ xs, int* __restrict__ idx,
                       float* __restrict__ vals) {
  const long total4 = (long)BB * VV / 4;
  const long stride = (long)gridDim.x * blockDim.x;
  for (long i = (long)blockIdx.x * blockDim.x + threadIdx.x; i < total4; i += stride) {
    float4 v = ((const float4*)xs)[i];
    if (v.x != 0.f || v.y != 0.f || v.z != 0.f || v.w != 0.f) {
      float vv[4] = {v.x, v.y, v.z, v.w};
#pragma unroll
      for (int c = 0; c < 4; c++) {
        if (vv[c] != 0.f) {
          long f = i * 4 + c;
          int b = (int)(f / VV);
          int p = (int)(f - (long)b * VV);
          idx[b] = p;
          vals[b] = vv[c];
        }
      }
    }
  }
}

// K2: EMBEDM f32 -> bf16 copy.
__global__ void k_cvt(const float* __restrict__ em, unsigned short* __restrict__ ebf) {
  const int total4 = VV * EE / 4;
  const int stride = gridDim.x * blockDim.x;
  for (int i = blockIdx.x * blockDim.x + threadIdx.x; i < total4; i += stride) {
    float4 v = ((const float4*)em)[i];
    ushort4 o;
    o.x = f2bf(v.x); o.y = f2bf(v.y); o.z = f2bf(v.z); o.w = f2bf(v.w);
    ((ushort4*)ebf)[i] = o;
  }
}

// K3: y[b] = (val * EMBEDM[idx[b]]) @ metric, stored bf16.
__global__ void k_embed(const float* __restrict__ em, const float* __restrict__ metric,
                        const int* __restrict__ idx, const float* __restrict__ vals,
                        unsigned short* __restrict__ ybf) {
  __shared__ float x[EE];
  const int b = blockIdx.x;
  const int e = threadIdx.x;
  const int row = idx[b];
  const float val = vals[b];
  x[e] = em[(long)row * EE + e] * val;
  __syncthreads();
  float acc = 0.f;
#pragma unroll
  for (int k = 0; k < EE; k++) acc = fmaf(x[k], metric[k * EE + e], acc);
  ybf[b * EE + e] = f2bf(acc);
}

// ---- GEMM scores = Y @ E^T, big tile: block = 256 rows x 1024 cols, 8 waves.
// Y: register-resident per wave (rows rg*64 + rf*16 + li). E: streamed through
// 2x16KB LDS dbuf (64-col chunks), global_load_lds + counted vmcnt(2).
// Swapped MFMA (A=E, B=Y): lane holds batch row (lane&15), vocab g*4+r per frag.

static __device__ __forceinline__ void stageE(const unsigned short* __restrict__ ebf,
                                              char* ldsbuf, int colbase, int w, int lane) {
#pragma unroll
  for (int i = 0; i < 2; i++) {
    const int G = (i * 8 + w) * 64 + lane;   // granule 0..1023 (16B each)
    const int c2 = G >> 4;                   // col within chunk
    const int gc = G & 15;                   // granule within 256B row
    int col = colbase + c2;
    col = col < VV ? col : VV - 1;           // clamp; masked in epilogue
    const char* src = (const char*)(ebf + (size_t)col * EE) + ((gc ^ (c2 & 7)) * 16);
    __builtin_amdgcn_global_load_lds((as1_void*)src,
                                     (as3_void*)(ldsbuf + (i * 8 + w) * 1024), 16, 0, 0);
  }
}

template <bool PASS_B, bool TAIL>
static __device__ __forceinline__ void gemm_body(const unsigned short* __restrict__ ybf,
                                                 const unsigned short* __restrict__ ebf,
                                                 char* __restrict__ ldsE,
                                                 float* __restrict__ pm, float* __restrict__ ps,
                                                 const float* __restrict__ lse,
                                                 float* __restrict__ out) {
  const int cbx = blockIdx.x;
  const int rowbase = blockIdx.y * RR;
  const int w = threadIdx.x >> 6;
  const int l = threadIdx.x & 63;
  const int g = l >> 4;
  const int li = l & 15;
  const int rg = w >> 1;                     // row-group 0..3 (64 rows each)
  const int cg = w & 1;                      // col-group 0..1 (32 cols of each chunk)
  const int cb = cbx * CC;

  // Y resident in registers: y[rf][kk], rows rowbase + rg*64 + rf*16 + li.
  bf16x8 y[4][4];
#pragma unroll
  for (int rf = 0; rf < 4; rf++) {
    const bf16x8* yv = (const bf16x8*)(ybf + (size_t)(rowbase + rg * 64 + rf * 16 + li) * EE);
#pragma unroll
    for (int kk = 0; kk < 4; kk++) y[rf][kk] = yv[kk * 4 + g];
  }

  float Lr[4];
  float m[4], s[4];
  if (PASS_B) {
#pragma unroll
    for (int rf = 0; rf < 4; rf++) Lr[rf] = lse[rowbase + rg * 64 + rf * 16 + li];
  } else {
#pragma unroll
    for (int rf = 0; rf < 4; rf++) { m[rf] = -INFINITY; s[rf] = 0.f; }
  }

  stageE(ebf, ldsE, cb + 0 * CH, w, l);
  stageE(ebf, ldsE + 16384, cb + 1 * CH, w, l);
  __builtin_amdgcn_sched_barrier(0);

#pragma unroll 2
  for (int k = 0; k < NCH; k++) {
    // Wait for stage(k); tolerate stage(k+1)'s 2 loads in flight.
    if (k < NCH - 1) asm volatile("s_waitcnt vmcnt(2)" ::: "memory");
    else             asm volatile("s_waitcnt vmcnt(0)" ::: "memory");
    __builtin_amdgcn_sched_barrier(0);
    __builtin_amdgcn_s_barrier();
    __builtin_amdgcn_sched_barrier(0);

    const char* cur = ldsE + (k & 1) * 16384;
    bf16x8 afr[2][4];
#pragma unroll
    for (int cf = 0; cf < 2; cf++) {
      const int c2 = cg * 32 + cf * 16 + li;
      const char* ebase = cur + c2 * 256;
#pragma unroll
      for (int kk = 0; kk < 4; kk++)
        afr[cf][kk] = *(const bf16x8*)(ebase + (((kk * 4 + g) ^ (li & 7)) * 16));
    }

    f32x4 acc[4][2];
#pragma unroll
    for (int rf = 0; rf < 4; rf++)
#pragma unroll
      for (int cf = 0; cf < 2; cf++) acc[rf][cf] = (f32x4){0.f, 0.f, 0.f, 0.f};
#pragma unroll
    for (int rf = 0; rf < 4; rf++)
#pragma unroll
      for (int cf = 0; cf < 2; cf++)
#pragma unroll
        for (int kk = 0; kk < 4; kk++)
          acc[rf][cf] = __builtin_amdgcn_mfma_f32_16x16x32_bf16(afr[cf][kk], y[rf][kk],
                                                                acc[rf][cf], 0, 0, 0);

    const int colk = cb + k * CH + cg * 32 + g * 4;   // + cf*16 + r

    if (!PASS_B) {
#pragma unroll
      for (int rf = 0; rf < 4; rf++) {
        float cm = -INFINITY;
#pragma unroll
        for (int cf = 0; cf < 2; cf++)
#pragma unroll
          for (int r = 0; r < 4; r++)
            if (!TAIL || colk + cf * 16 + r < VV) cm = fmaxf(cm, acc[rf][cf][r]);
        const float mn = fmaxf(m[rf], cm);
        if (!TAIL || mn > -INFINITY) {
          float as = s[rf] * __expf(m[rf] - mn);
#pragma unroll
          for (int cf = 0; cf < 2; cf++)
#pragma unroll
            for (int r = 0; r < 4; r++)
              if (!TAIL || colk + cf * 16 + r < VV) as += __expf(acc[rf][cf][r] - mn);
          s[rf] = as; m[rf] = mn;
        }
      }
    } else {
#pragma unroll
      for (int rf = 0; rf < 4; rf++) {
        float* orow = out + (size_t)(rowbase + rg * 64 + rf * 16 + li) * VV;
#pragma unroll
        for (int cf = 0; cf < 2; cf++) {
          const int c = colk + cf * 16;
          if (!TAIL || c + 3 < VV) {
            f32x4 v;
#pragma unroll
            for (int r = 0; r < 4; r++) v[r] = acc[rf][cf][r] - Lr[rf];
            *(f32x4u*)(orow + c) = v;
          } else {
#pragma unroll
            for (int r = 0; r < 4; r++)
              if (c + r < VV) orow[c + r] = acc[rf][cf][r] - Lr[rf];
          }
        }
      }
    }

    __builtin_amdgcn_sched_barrier(0);
    __builtin_amdgcn_s_barrier();             // all waves done reading buf(k&1)
    __builtin_amdgcn_sched_barrier(0);
    if (k + 2 < NCH) stageE(ebf, ldsE + (k & 1) * 16384, cb + (k + 2) * CH, w, l);
    __builtin_amdgcn_sched_barrier(0);
  }

  if (!PASS_B) {
    // Merge g-groups: lanes l, l^16, l^32, l^48 share the same batch rows.
#pragma unroll
    for (int off = 16; off <= 32; off <<= 1) {
#pragma unroll
      for (int rf = 0; rf < 4; rf++) {
        const float mo = __shfl_xor(m[rf], off);
        const float so = __shfl_xor(s[rf], off);
        const float mn = fmaxf(m[rf], mo);
        float sn;
        if (mn == -INFINITY) sn = 0.f;
        else sn = s[rf] * __expf(m[rf] - mn) + so * __expf(mo - mn);
        m[rf] = mn; s[rf] = sn;
      }
    }
    // Merge the cg wave-pair via LDS scratch (reuse ldsE; loop is done).
    float* scm = (float*)ldsE;                // 512 m + 512 s floats
    float* scs = scm + 512;
    __syncthreads();
    if (l < 16) {
#pragma unroll
      for (int rf = 0; rf < 4; rf++) {
        const int slot = ((rg * 2 + cg) * 4 + rf) * 16 + li;
        scm[slot] = m[rf]; scs[slot] = s[rf];
      }
    }
    __syncthreads();
    const int t = threadIdx.x;
    if (t < 256) {
      const int trg = t >> 6, trf = (t >> 4) & 3, tli = t & 15;
      const int s0 = ((trg * 2 + 0) * 4 + trf) * 16 + tli;
      const int s1 = ((trg * 2 + 1) * 4 + trf) * 16 + tli;
      const float m0 = scm[s0], m1 = scm[s1];
      const float mn = fmaxf(m0, m1);
      float sn;
      if (mn == -INFINITY) sn = 0.f;
      else sn = scs[s0] * __expf(m0 - mn) + scs[s1] * __expf(m1 - mn);
      const int grow = rowbase + trg * 64 + trf * 16 + tli;
      pm[(size_t)cbx * BB + grow] = mn;
      ps[(size_t)cbx * BB + grow] = sn;
    }
  }
}

__global__ __launch_bounds__(512, 2) void k_gemm_a(const unsigned short* __restrict__ ybf,
                                                   const unsigned short* __restrict__ ebf,
                                                   float* __restrict__ pm,
                                                   float* __restrict__ ps) {
  __shared__ char ldsE[2][16384];
  if (blockIdx.x < NCB - 1)
    gemm_body<false, false>(ybf, ebf, ldsE[0], pm, ps, nullptr, nullptr);
  else
    gemm_body<false, true>(ybf, ebf, ldsE[0], pm, ps, nullptr, nullptr);
}

__global__ __launch_bounds__(512, 2) void k_gemm_b(const unsigned short* __restrict__ ybf,
                                                   const unsigned short* __restrict__ ebf,
                                                   const float* __restrict__ lse,
                                                   float* __restrict__ out) {
  __shared__ char ldsE[2][16384];
  if (blockIdx.x < NCB - 1)
    gemm_body<true, false>(ybf, ebf, ldsE[0], nullptr, nullptr, lse, out);
  else
    gemm_body<true, true>(ybf, ebf, ldsE[0], nullptr, nullptr, lse, out);
}

// K5: combine per-col-block partials into lse per row. One wave per row.
__global__ void k_lse(const float* __restrict__ pm, const float* __restrict__ ps,
                      float* __restrict__ lse) {
  const int row = blockIdx.x;
  const int t = threadIdx.x;   // 64
  float m = (t < NCB) ? pm[(size_t)t * BB + row] : -INFINITY;
#pragma unroll
  for (int off = 32; off; off >>= 1) m = fmaxf(m, __shfl_xor(m, off));
  float s = (t < NCB) ? ps[(size_t)t * BB + row] * __expf(pm[(size_t)t * BB + row] - m) : 0.f;
#pragma unroll
  for (int off = 32; off; off >>= 1) s += __shfl_xor(s, off);
  if (t == 0) lse[row] = m + logf(s);
}

extern "C" void kernel_launch(void* const* d_in, const int* in_sizes, int n_in,
                              void* d_out, int out_size, void* d_ws, size_t ws_size,
                              hipStream_t stream) {
  const float* xs = (const float*)d_in[0];
  const float* em = (const float*)d_in[1];
  const float* metric = (const float*)d_in[2];
  float* out = (float*)d_out;

  char* w = (char*)d_ws;
  int* idx = (int*)(w + 0);                                   // 4 KB
  float* vals = (float*)(w + 4096);                           // 4 KB
  float* lse = (float*)(w + 8192);                            // 4 KB
  unsigned short* ybf = (unsigned short*)(w + 12288);         // 256 KB
  unsigned short* ebf = (unsigned short*)(w + 12288 + 262144);              // 12.87 MB
  float* pm = (float*)(w + 12288 + 262144 + 12865792);                      // 200 KB
  float* ps = (float*)(w + 12288 + 262144 + 12865792 + (size_t)NCB * BB * 4);

  k_scan<<<2048, 256, 0, stream>>>(xs, idx, vals);
  k_cvt<<<2048, 256, 0, stream>>>(em, ebf);
  k_embed<<<BB, EE, 0, stream>>>(em, metric, idx, vals, ybf);
  k_gemm_a<<<dim3(NCB, BB / RR), 512, 0, stream>>>(ybf, ebf, pm, ps);
  k_lse<<<BB, 64, 0, stream>>>(pm, ps, lse);
  k_gemm_b<<<dim3(NCB, BB / RR), 512, 0, stream>>>(ybf, ebf, lse, out);
}